// Round 6
// baseline (119.843 us; speedup 1.0000x reference)
//
#include <hip/hip_runtime.h>
#include <hip/hip_bf16.h>
#include <stdint.h>

typedef __attribute__((ext_vector_type(8))) short short8;
typedef __attribute__((ext_vector_type(4))) float f32x4;
typedef unsigned short u16;

#define AS1 __attribute__((address_space(1)))
#define AS3 __attribute__((address_space(3)))

__device__ __forceinline__ u16 f2b(float f) {
  union { float f; uint32_t u; } c; c.f = f;
  uint32_t u = c.u;
  return (u16)((u + 0x7fffu + ((u >> 16) & 1u)) >> 16);  // RNE
}
__device__ __forceinline__ float b2f(u16 b) {
  union { uint32_t u; float f; } c; c.u = ((uint32_t)b) << 16;
  return c.f;
}

// ---------------- conversion kernels (verified round 1) ----------------
__global__ void cvt_bf16_kernel(const float* __restrict__ src,
                                u16* __restrict__ dst, int n4) {
  int i = blockIdx.x * blockDim.x + threadIdx.x;
  if (i >= n4) return;
  const float4 v = reinterpret_cast<const float4*>(src)[i];
  ushort4 o;
  o.x = f2b(v.x); o.y = f2b(v.y); o.z = f2b(v.z); o.w = f2b(v.w);
  reinterpret_cast<ushort4*>(dst)[i] = o;
}

__global__ void cvt_transpose_kernel(const float* __restrict__ w0,
                                     const float* __restrict__ w1,
                                     const float* __restrict__ w2,
                                     u16* __restrict__ d0,
                                     u16* __restrict__ d1,
                                     u16* __restrict__ d2,
                                     int K, int N) {
  const float* src = (blockIdx.y == 0) ? w0 : (blockIdx.y == 1 ? w1 : w2);
  u16* dst = (blockIdx.y == 0) ? d0 : (blockIdx.y == 1 ? d1 : d2);
  int idx = blockIdx.x * blockDim.x + threadIdx.x;
  if (idx >= K * N) return;
  int k = idx / N, n = idx - k * N;
  dst[(size_t)n * K + k] = f2b(src[idx]);
}

// -------- 8-phase, register-pipelined (reads one phase ahead) GEMM --------
// C[16384,N] = A[.,1024] @ Wt[N][1024]^T.  BM=256, BK=64, NT=16 tiles,
// 8 iters x 2 tiles (even->dbuf0, odd->dbuf1).  512 thr = 8 waves.
// GATES: BN=256, 2Mx4N waves (wave 128x64, MQ=4).  CAND: BN=128, 4Mx2N
// (wave 64x64, MQ=2).
// KEY CHANGE vs r5: each phase p does  [lgkm0(waits reads issued @p-1);
// issue ds_reads for p+1; issue stages; sched_barrier; MFMA(p) on regs
// loaded @p-1; (VMW); barrier]  -> LDS pipe crunches p+1's reads UNDER
// MFMA(p); lgkm0 is ~free.  Register sets rotate: aA=LO, aB=HI halves;
// bA/bB = b01 even/odd tile, bC = b23 shared.
// Consumption: ph0 aA*bA, ph1 aA*bC, ph2 aB*bC, ph3 aB*bA (dbuf0);
// ph4..7 mirror on dbuf1 with bB.  Read-issues: ph0:bC(d0) ph1:aB(d0)
// ph3:aA,bB(d1) ph4:bC(d1) ph5:aB(d1) ph7:aA,bA(d0,tile e').
// Region freedom (stage ph >= last-read-issue+2, barrier-separated):
// d0: B free@ph2, A free@ph3; d1: B free@ph6, A free@ph7.
// Stage stream (e'=2j+2, o'=2j+3): ph2:B(e') ph3:A0(e') ph4:A1(e')
// ph6:B0(o') ph7:[B1(o')],A0(o'),A1(o').
// Deadlines: tile o (first read ph3) landed by ph2-end VMW(4|2): drains
// o's loads (issued prev ph6/ph7), allows only ph2's own.  Tile e'
// (first read ph7) by ph6-end VMW(2): drains through ph4.  Last iter: 0.
// Swizzle + numerics identical to r3/r5 (0 bank conflicts, absmax .0156).

#define BAR() do { __builtin_amdgcn_s_barrier(); __builtin_amdgcn_sched_barrier(0); } while (0)
#define SB() __builtin_amdgcn_sched_barrier(0)
#define LGKM0() do { asm volatile("s_waitcnt lgkmcnt(0)" ::: "memory"); __builtin_amdgcn_sched_barrier(0); } while (0)
#define VMW(n) do { asm volatile("s_waitcnt vmcnt(" #n ")" ::: "memory"); __builtin_amdgcn_sched_barrier(0); } while (0)

template <int GATES>
__global__ __launch_bounds__(512, 1) void gemm8_kernel(
    const u16* __restrict__ a1,    // A cols 0..511    [16384,512] bf16
    const u16* __restrict__ a2,    // A cols 512..1023 [16384,512] bf16
    const u16* __restrict__ wt,    // weights^T [N][1024] bf16
    const u16* __restrict__ hb,    // h_prev bf16 [16384,512]
    const u16* __restrict__ zb_in, // z bf16 (cand)
    u16* __restrict__ o_z,         // gates
    u16* __restrict__ o_rh,        // gates
    float* __restrict__ o_f) {     // cand
  constexpr int NT = 16;
  constexpr int NITER = 8;
  constexpr int BN = GATES ? 256 : 128;
  constexpr int MQ = GATES ? 4 : 2;            // a-frags per half
  constexpr int AHALF = GATES ? 16384 : 8192;  // per-wave A wm-stride bytes
  constexpr int DBUF_E = GATES ? 32768 : 24576;
  constexpr int DB1B = DBUF_E * 2;             // dbuf1 byte offset

  __shared__ u16 lds[2 * DBUF_E];
  const char* ldsb = (const char*)lds;

  const int tid = threadIdx.x;
  const int lane = tid & 63;
  const int wid = tid >> 6;
  const int wm = GATES ? (wid >> 2) : (wid >> 1);
  const int wn = GATES ? (wid & 3) : (wid & 1);

  // XCD-chunked bijective swizzle (grid 256 = 8*32)
  const int wg = ((int)blockIdx.x & 7) * 32 + ((int)blockIdx.x >> 3);
  const int bn = wg & 3;
  const int bm = wg >> 2;

  // ---- staging (verified r5): one inst = 512 lanes x 16B = 64 rows x 128B
  const int srow8 = tid >> 3;
  const int swzb = ((tid & 7) ^ (srow8 & 7)) << 4;
  auto STAGE = [&](int t, int kind) {
    if (t >= NT) return;
    u16* dst = lds + (t & 1) * DBUF_E + kind * 8192 + wid * 512;
    if (kind < 2) {  // A half
      const char* src = ((t < 8) ? ((const char*)a1 + (size_t)t * 128)
                                 : ((const char*)a2 + (size_t)(t - 8) * 128)) +
                        (size_t)(bm * 256 + kind * 128 + srow8) * 1024 + swzb;
      __builtin_amdgcn_global_load_lds((const AS1 void*)src, (AS3 void*)dst, 16, 0, 0);
      __builtin_amdgcn_global_load_lds((const AS1 void*)(src + 65536), (AS3 void*)(dst + 4096), 16, 0, 0);
    } else {         // B half
      const char* src = (const char*)wt +
                        (size_t)(bn * BN + (kind - 2) * 128 + srow8) * 2048 +
                        (size_t)t * 128 + swzb;
      __builtin_amdgcn_global_load_lds((const AS1 void*)src, (AS3 void*)dst, 16, 0, 0);
      __builtin_amdgcn_global_load_lds((const AS1 void*)(src + 131072), (AS3 void*)(dst + 4096), 16, 0, 0);
    }
  };

  // ---- frag-read addressing (verified r5)
  const int rsel = lane & 15;
  const int kg = lane >> 4;
  const int sl0 = (kg ^ (rsel & 7)) << 4;
  const int sl1 = ((4 + kg) ^ (rsel & 7)) << 4;
  const int aoff0 = wm * AHALF + rsel * 128;
  const int boff0 = 32768 + wn * 8192 + rsel * 128;

  f32x4 acc[2 * MQ][4] = {};
  short8 aA[MQ][2], aB[MQ][2];        // A LO / HI halves
  short8 bA[2][2], bB[2][2], bC[2][2];  // b01 even / b01 odd / b23 shared

  auto RD_A = [&](auto& dst, int DB, int mfb) {
#pragma unroll
    for (int mi = 0; mi < MQ; ++mi) {
      dst[mi][0] = *(const short8*)(ldsb + DB + aoff0 + (mfb + mi) * 2048 + sl0);
      dst[mi][1] = *(const short8*)(ldsb + DB + aoff0 + (mfb + mi) * 2048 + sl1);
    }
  };
  auto RD_B = [&](auto& dst, int DB, int nfb) {
#pragma unroll
    for (int ni = 0; ni < 2; ++ni) {
      dst[ni][0] = *(const short8*)(ldsb + DB + boff0 + (nfb + ni) * 2048 + sl0);
      dst[ni][1] = *(const short8*)(ldsb + DB + boff0 + (nfb + ni) * 2048 + sl1);
    }
  };
  auto MM = [&](auto& A, auto& Bv, int mb, int nb) {
    __builtin_amdgcn_s_setprio(1);
#pragma unroll
    for (int mi = 0; mi < MQ; ++mi)
#pragma unroll
      for (int ni = 0; ni < 2; ++ni) {
        acc[mb + mi][nb + ni] = __builtin_amdgcn_mfma_f32_16x16x32_bf16(A[mi][0], Bv[ni][0], acc[mb + mi][nb + ni], 0, 0, 0);
        acc[mb + mi][nb + ni] = __builtin_amdgcn_mfma_f32_16x16x32_bf16(A[mi][1], Bv[ni][1], acc[mb + mi][nb + ni], 0, 0, 0);
      }
    __builtin_amdgcn_s_setprio(0);
  };

  // ---- prologue: tile0 fully + tile1 fully in flight; wait tile0 only
  STAGE(0, 2); if constexpr (GATES) STAGE(0, 3);
  STAGE(0, 0); STAGE(0, 1);
  STAGE(1, 2); if constexpr (GATES) STAGE(1, 3);
  STAGE(1, 0); STAGE(1, 1);
  if constexpr (GATES) VMW(8); else VMW(6);
  BAR();
  RD_A(aA, 0, 0); RD_B(bA, 0, 0);

#pragma unroll 1
  for (int j = 0; j < NITER; ++j) {
    const int e2 = 2 * j + 2, o2 = 2 * j + 3;
    const bool stg = e2 < NT;
    // ph0: MFMA(aA,bA) tile-even; read b23(d0)
    LGKM0(); RD_B(bC, 0, 2); SB();
    MM(aA, bA, 0, 0); BAR();
    // ph1: read aHI(d0)
    LGKM0(); RD_A(aB, 0, MQ); SB();
    MM(aA, bC, 0, 2); BAR();
    // ph2: stage B(e'); VMW -> tile-odd landed
    LGKM0();
    if (stg) { STAGE(e2, 2); if constexpr (GATES) STAGE(e2, 3); }
    SB();
    MM(aB, bC, MQ, 2);
    if (stg) { if constexpr (GATES) VMW(4); else VMW(2); } else VMW(0);
    BAR();
    // ph3: read aLO,b01 (d1); stage A0(e')
    LGKM0(); RD_A(aA, DB1B, 0); RD_B(bB, DB1B, 0);
    if (stg) STAGE(e2, 0);
    SB();
    MM(aB, bA, MQ, 0); BAR();
    // ph4: read b23(d1); stage A1(e')
    LGKM0(); RD_B(bC, DB1B, 2);
    if (stg) STAGE(e2, 1);
    SB();
    MM(aA, bB, 0, 0); BAR();
    // ph5: read aHI(d1)
    LGKM0(); RD_A(aB, DB1B, MQ); SB();
    MM(aA, bC, 0, 2); BAR();
    // ph6: stage B0(o'); VMW -> tile e' landed
    LGKM0();
    if (o2 < NT) STAGE(o2, 2);
    SB();
    MM(aB, bC, MQ, 2);
    if (stg) VMW(2); else VMW(0);
    BAR();
    // ph7: read aLO,b01 (d0, tile e'); stage rest of o'
    LGKM0();
    if (j < NITER - 1) { RD_A(aA, 0, 0); RD_B(bA, 0, 0); }
    if (o2 < NT) { if constexpr (GATES) STAGE(o2, 3); STAGE(o2, 0); STAGE(o2, 1); }
    SB();
    MM(aB, bB, MQ, 0); BAR();
  }

  // ---- epilogue.  C/D: col=rsel, row=kg*4+q (verified r3).
  const int row0 = bm * 256 + wm * (GATES ? 128 : 64) + kg * 4;
  const int col0 = bn * BN + wn * 64 + rsel;
  if constexpr (GATES) {
    if (bn < 2) {  // z half (global cols 0..511), block-uniform
#pragma unroll
      for (int mf = 0; mf < 8; ++mf)
#pragma unroll
        for (int nf = 0; nf < 4; ++nf)
#pragma unroll
          for (int q = 0; q < 4; ++q) {
            const int row = row0 + mf * 16 + q;
            const int col = col0 + nf * 16;
            const float zf = 1.f / (1.f + __expf(-acc[mf][nf][q]));
            o_z[(size_t)row * 512 + col] = f2b(zf);
          }
    } else {       // r half (global cols 512..1023)
#pragma unroll
      for (int mf = 0; mf < 8; ++mf)
#pragma unroll
        for (int nf = 0; nf < 4; ++nf)
#pragma unroll
          for (int q = 0; q < 4; ++q) {
            const int row = row0 + mf * 16 + q;
            const int col = col0 + nf * 16 - 512;
            const size_t idx = (size_t)row * 512 + col;
            const float rf = 1.f / (1.f + __expf(-acc[mf][nf][q]));
            o_rh[idx] = f2b(rf * b2f(hb[idx]));
          }
    }
  } else {
#pragma unroll
    for (int mf = 0; mf < 4; ++mf)
#pragma unroll
      for (int nf = 0; nf < 4; ++nf)
#pragma unroll
        for (int q = 0; q < 4; ++q) {
          const int row = row0 + mf * 16 + q;
          const int col = col0 + nf * 16;
          const size_t idx = (size_t)row * 512 + col;
          const float s = acc[mf][nf][q];
          const float hh = 2.f / (1.f + __expf(-2.f * s)) - 1.f;  // tanh
          const float z = b2f(zb_in[idx]);
          o_f[idx] = z * b2f(hb[idx]) + (1.f - z) * hh;
        }
  }
}

// ---------------- launch ----------------
extern "C" void kernel_launch(void* const* d_in, const int* in_sizes, int n_in,
                              void* d_out, int out_size, void* d_ws, size_t ws_size,
                              hipStream_t stream) {
  const float* inputs = (const float*)d_in[0];
  const float* h_prev = (const float*)d_in[1];
  const float* Wz = (const float*)d_in[2];
  const float* Wr = (const float*)d_in[3];
  const float* Wh = (const float*)d_in[4];
  float* out = (float*)d_out;

  const int B = 16384, D = 512, U = 512, K = 1024;

  u16* xb = (u16*)d_ws;                 // [B,D] bf16
  u16* hb = xb + (size_t)B * D;         // [B,U] bf16
  u16* wzt = hb + (size_t)B * U;        // [1024,1024]: rows 0-511 Wz^T, 512-1023 Wr^T
  u16* wrt = wzt + (size_t)K * U;
  u16* wht = wrt + (size_t)K * U;       // [512,1024] Wh^T
  u16* zb = wht + (size_t)K * U;        // [B,U] bf16
  u16* rhb = zb + (size_t)B * U;        // [B,U] bf16

  const int n4 = (B * D) / 4;
  cvt_bf16_kernel<<<(n4 + 255) / 256, 256, 0, stream>>>(inputs, xb, n4);
  cvt_bf16_kernel<<<(n4 + 255) / 256, 256, 0, stream>>>(h_prev, hb, n4);
  dim3 tg((K * U + 255) / 256, 3);
  cvt_transpose_kernel<<<tg, 256, 0, stream>>>(Wz, Wr, Wh, wzt, wrt, wht, K, U);

  // gates: N=1024 (z|r), BN=256 -> grid 256 blocks, full chip
  gemm8_kernel<1><<<dim3(256), 512, 0, stream>>>(xb, hb, wzt, hb, nullptr, zb, rhb, nullptr);
  // candidate: N=512, BN=128 -> grid 256 blocks, full chip
  gemm8_kernel<0><<<dim3(256), 512, 0, stream>>>(xb, rhb, wht, hb, zb, nullptr, nullptr, out);
}

// Round 7
// 101.892 us; speedup vs baseline: 1.1762x; 1.1762x over previous
//
#include <hip/hip_runtime.h>
#include <hip/hip_bf16.h>
#include <stdint.h>

typedef __attribute__((ext_vector_type(8))) short short8;
typedef __attribute__((ext_vector_type(4))) float f32x4;
typedef unsigned short u16;

#define AS1 __attribute__((address_space(1)))
#define AS3 __attribute__((address_space(3)))

__device__ __forceinline__ u16 f2b(float f) {
  union { float f; uint32_t u; } c; c.f = f;
  uint32_t u = c.u;
  return (u16)((u + 0x7fffu + ((u >> 16) & 1u)) >> 16);  // RNE
}
__device__ __forceinline__ float b2f(u16 b) {
  union { uint32_t u; float f; } c; c.u = ((uint32_t)b) << 16;
  return c.f;
}

// ---------------- conversion kernels (verified round 1) ----------------
__global__ void cvt_bf16_kernel(const float* __restrict__ src,
                                u16* __restrict__ dst, int n4) {
  int i = blockIdx.x * blockDim.x + threadIdx.x;
  if (i >= n4) return;
  const float4 v = reinterpret_cast<const float4*>(src)[i];
  ushort4 o;
  o.x = f2b(v.x); o.y = f2b(v.y); o.z = f2b(v.z); o.w = f2b(v.w);
  reinterpret_cast<ushort4*>(dst)[i] = o;
}

__global__ void cvt_transpose_kernel(const float* __restrict__ w0,
                                     const float* __restrict__ w1,
                                     const float* __restrict__ w2,
                                     u16* __restrict__ d0,
                                     u16* __restrict__ d1,
                                     u16* __restrict__ d2,
                                     int K, int N) {
  const float* src = (blockIdx.y == 0) ? w0 : (blockIdx.y == 1 ? w1 : w2);
  u16* dst = (blockIdx.y == 0) ? d0 : (blockIdx.y == 1 ? d1 : d2);
  int idx = blockIdx.x * blockDim.x + threadIdx.x;
  if (idx >= K * N) return;
  int k = idx / N, n = idx - k * N;
  dst[(size_t)n * K + k] = f2b(src[idx]);
}

#define BAR() do { __builtin_amdgcn_s_barrier(); __builtin_amdgcn_sched_barrier(0); } while (0)
#define LGKM0() do { asm volatile("s_waitcnt lgkmcnt(0)" ::: "memory"); __builtin_amdgcn_sched_barrier(0); } while (0)
#define VMW(n) do { asm volatile("s_waitcnt vmcnt(" #n ")" ::: "memory"); __builtin_amdgcn_sched_barrier(0); } while (0)

// ---------------- GATES: r5-verbatim 8-phase structure ----------------
// C[16384,1024] = [x|h] @ [Wz^T;Wr^T]^T.  BM=256, BN=256, BK=64, NT=16,
// 8 iters x 2 tiles.  512 thr = 8 waves 2Mx4N (wave 128x64, MQ=4).
// (Schedule, swizzle, vmcnt derivation verified passing in round 5.)
__global__ __launch_bounds__(512, 1) void gemm_gates_kernel(
    const u16* __restrict__ xb, const u16* __restrict__ hb,
    const u16* __restrict__ wt,
    u16* __restrict__ o_z, u16* __restrict__ o_rh) {
  constexpr int NT = 16, NITER = 8;
  __shared__ u16 lds[65536];          // 2 dbuf x 32768 e (A 32KB + B 32KB)
  const char* ldsb = (const char*)lds;

  const int tid = threadIdx.x;
  const int lane = tid & 63;
  const int wid = tid >> 6;
  const int wm = wid >> 2, wn = wid & 3;
  const int wg = ((int)blockIdx.x & 7) * 32 + ((int)blockIdx.x >> 3);
  const int bn = wg & 3, bm = wg >> 2;

  const int srow8 = tid >> 3;
  const int swzb = ((tid & 7) ^ (srow8 & 7)) << 4;
  auto STAGE = [&](int t, int kind) {
    if (t >= NT) return;
    u16* dst = lds + (t & 1) * 32768 + kind * 8192 + wid * 512;
    if (kind < 2) {  // A half (128 rows)
      const char* src = ((t < 8) ? ((const char*)xb + (size_t)t * 128)
                                 : ((const char*)hb + (size_t)(t - 8) * 128)) +
                        (size_t)(bm * 256 + kind * 128 + srow8) * 1024 + swzb;
      __builtin_amdgcn_global_load_lds((const AS1 void*)src, (AS3 void*)dst, 16, 0, 0);
      __builtin_amdgcn_global_load_lds((const AS1 void*)(src + 65536), (AS3 void*)(dst + 4096), 16, 0, 0);
    } else {         // B half (128 rows of the 256-row Wt tile)
      const char* src = (const char*)wt +
                        (size_t)(bn * 256 + (kind - 2) * 128 + srow8) * 2048 +
                        (size_t)t * 128 + swzb;
      __builtin_amdgcn_global_load_lds((const AS1 void*)src, (AS3 void*)dst, 16, 0, 0);
      __builtin_amdgcn_global_load_lds((const AS1 void*)(src + 131072), (AS3 void*)(dst + 4096), 16, 0, 0);
    }
  };

  const int rsel = lane & 15;
  const int kg = lane >> 4;
  const int sl0 = (kg ^ (rsel & 7)) << 4;
  const int sl1 = ((4 + kg) ^ (rsel & 7)) << 4;
  const int aoff0 = wm * 16384 + rsel * 128;
  const int boff0 = 32768 + wn * 8192 + rsel * 128;

  f32x4 acc[8][4] = {};
  short8 a[4][2], b[4][2];

  auto ldA = [&](int DB, int mfb) {
#pragma unroll
    for (int mi = 0; mi < 4; ++mi) {
      a[mi][0] = *(const short8*)(ldsb + DB + aoff0 + (mfb + mi) * 2048 + sl0);
      a[mi][1] = *(const short8*)(ldsb + DB + aoff0 + (mfb + mi) * 2048 + sl1);
    }
  };
  auto ldB = [&](int DB, int nfb) {
#pragma unroll
    for (int ni = 0; ni < 2; ++ni) {
      b[nfb + ni][0] = *(const short8*)(ldsb + DB + boff0 + (nfb + ni) * 2048 + sl0);
      b[nfb + ni][1] = *(const short8*)(ldsb + DB + boff0 + (nfb + ni) * 2048 + sl1);
    }
  };
  auto MM = [&](int mb, int nb) {   // ksub-reordered: 8 indep MFMAs between dep pairs
    __builtin_amdgcn_s_setprio(1);
#pragma unroll
    for (int ks = 0; ks < 2; ++ks)
#pragma unroll
      for (int mi = 0; mi < 4; ++mi)
#pragma unroll
        for (int ni = 0; ni < 2; ++ni)
          acc[mb + mi][nb + ni] = __builtin_amdgcn_mfma_f32_16x16x32_bf16(
              a[mi][ks], b[nb + ni][ks], acc[mb + mi][nb + ni], 0, 0, 0);
    __builtin_amdgcn_s_setprio(0);
  };

  STAGE(0, 2); STAGE(0, 3); STAGE(0, 0); STAGE(0, 1); STAGE(1, 2); STAGE(1, 3);
  VMW(4); BAR();

#pragma unroll 1
  for (int j = 0; j < NITER; ++j) {
    const int t1 = 2 * j + 1, t2 = 2 * j + 2, t3 = 2 * j + 3;
    // ph0
    ldA(0, 0); ldB(0, 0); STAGE(t1, 0);
    BAR(); LGKM0(); MM(0, 0); BAR();
    // ph1
    ldB(0, 2); STAGE(t1, 1);
    BAR(); LGKM0(); MM(0, 2); BAR();
    // ph2
    ldA(0, 4); STAGE(t2, 2);
    BAR(); LGKM0(); MM(4, 2); BAR();
    // ph3
    STAGE(t2, 3);
    BAR(); MM(4, 0);
    if (j == NITER - 1) { VMW(0); } else { VMW(4); }
    BAR();
    // ph4
    ldA(65536, 0); ldB(65536, 0); STAGE(t2, 0);
    BAR(); LGKM0(); MM(0, 0); BAR();
    // ph5
    ldB(65536, 2); STAGE(t2, 1);
    BAR(); LGKM0(); MM(0, 2); BAR();
    // ph6
    ldA(65536, 4); STAGE(t3, 2);
    BAR(); LGKM0(); MM(4, 2); BAR();
    // ph7
    STAGE(t3, 3);
    BAR(); MM(4, 0);
    if (j == NITER - 1) { VMW(0); } else { VMW(4); }
    BAR();
  }

  const int row0 = bm * 256 + wm * 128 + kg * 4;
  const int col0 = bn * 256 + wn * 64 + rsel;
  if (bn < 2) {  // z half (global cols 0..511), block-uniform
#pragma unroll
    for (int mf = 0; mf < 8; ++mf)
#pragma unroll
      for (int nf = 0; nf < 4; ++nf)
#pragma unroll
        for (int q = 0; q < 4; ++q) {
          const int row = row0 + mf * 16 + q;
          const int col = col0 + nf * 16;
          const float zf = 1.f / (1.f + __expf(-acc[mf][nf][q]));
          o_z[(size_t)row * 512 + col] = f2b(zf);
        }
  } else {       // r half (global cols 512..1023)
#pragma unroll
    for (int mf = 0; mf < 8; ++mf)
#pragma unroll
      for (int nf = 0; nf < 4; ++nf)
#pragma unroll
        for (int q = 0; q < 4; ++q) {
          const int row = row0 + mf * 16 + q;
          const int col = col0 + nf * 16 - 512;
          const size_t idx = (size_t)row * 512 + col;
          const float rf = 1.f / (1.f + __expf(-acc[mf][nf][q]));
          o_rh[idx] = f2b(rf * b2f(hb[idx]));
        }
  }
}

// ---------------- CAND: 4-phase/tile-pair, 2Mx4N waves ----------------
// C[16384,512] = [x|rh] @ Wh^T.  BM=256, BN=128, BK=64, NT=16, 8 iters x
// 2 tiles in 4 phases.  Waves 2Mx4N: per-wave 128x32 (MQ=4, 2 B-frags) ->
// 16 MFMA/phase (gates density at half the phase count).
// LDS 144KB: d0A[32K]@0, d0B[16K]@32768, oddA[2]x32K@49152, oddB[2]x16K
// @114688 (odd tiles 2-deep so stages can issue early).
// Stage stream iter j (e2=2j+2, o2=2j+3, ps=(j+1)&1):
//   ph0: A0(o2)->oddA[ps];  ph1: A1(o2)->oddA[ps], B(e2)->d0B;
//   ph2: A0(e2),A1(e2)->d0A, B(o2)->oddB[ps];  ph3: none.
// WAR (all stage-issues >= 1 barrier after the region's last read-issue):
//   d0A read ph0/ph1 -> staged ph2; d0B read ph0 -> ph1; oddA[ps] read
//   prev iter ph2/ph3 -> ph0; oddB[ps] read prev iter ph2 -> ph2.  OK.
// Deadlines: e2 (read next ph0) last half A1@ph2 + later-issued B(o2)=2
//   -> VMW(2)@ph3-end.  o2 (read next ph2) last half B@ph2 + later = ph0(2)
//   +ph1(4) of next iter -> VMW(6)@ph1-end.  Last iter: VMW(0) both.
__global__ __launch_bounds__(512, 1) void gemm_cand_kernel(
    const u16* __restrict__ xb, const u16* __restrict__ rhb,
    const u16* __restrict__ wt, const u16* __restrict__ hb,
    const u16* __restrict__ zb_in, float* __restrict__ o_f) {
  constexpr int NT = 16;
  __shared__ u16 lds[73728];          // 147456 B
  const char* ldsb = (const char*)lds;

  const int tid = threadIdx.x;
  const int lane = tid & 63;
  const int wid = tid >> 6;
  const int wm = wid >> 2, wn = wid & 3;
  const int wg = ((int)blockIdx.x & 7) * 32 + ((int)blockIdx.x >> 3);
  const int bn = wg & 3, bm = wg >> 2;

  const int srow8 = tid >> 3;
  const int swzb = ((tid & 7) ^ (srow8 & 7)) << 4;
  auto STG_A = [&](int t, int half, int regionByte) {
    if (t >= NT) return;
    u16* dst = lds + regionByte / 2 + half * 8192 + wid * 512;
    const char* src = ((t < 8) ? ((const char*)xb + (size_t)t * 128)
                               : ((const char*)rhb + (size_t)(t - 8) * 128)) +
                      (size_t)(bm * 256 + half * 128 + srow8) * 1024 + swzb;
    __builtin_amdgcn_global_load_lds((const AS1 void*)src, (AS3 void*)dst, 16, 0, 0);
    __builtin_amdgcn_global_load_lds((const AS1 void*)(src + 65536), (AS3 void*)(dst + 4096), 16, 0, 0);
  };
  auto STG_B = [&](int t, int regionByte) {
    if (t >= NT) return;
    u16* dst = lds + regionByte / 2 + wid * 512;
    const char* src = (const char*)wt + (size_t)(bn * 128 + srow8) * 2048 +
                      (size_t)t * 128 + swzb;
    __builtin_amdgcn_global_load_lds((const AS1 void*)src, (AS3 void*)dst, 16, 0, 0);
    __builtin_amdgcn_global_load_lds((const AS1 void*)(src + 131072), (AS3 void*)(dst + 4096), 16, 0, 0);
  };

  const int rsel = lane & 15;
  const int kg = lane >> 4;
  const int sl0 = (kg ^ (rsel & 7)) << 4;
  const int sl1 = ((4 + kg) ^ (rsel & 7)) << 4;
  const int aoff0 = wm * 16384 + rsel * 128;
  const int boff0 = wn * 4096 + rsel * 128;

  f32x4 acc[8][2] = {};
  short8 a[4][2], b[2][2];

  auto RD_A = [&](int regionByte, int mfb) {
#pragma unroll
    for (int mi = 0; mi < 4; ++mi) {
      a[mi][0] = *(const short8*)(ldsb + regionByte + aoff0 + (mfb + mi) * 2048 + sl0);
      a[mi][1] = *(const short8*)(ldsb + regionByte + aoff0 + (mfb + mi) * 2048 + sl1);
    }
  };
  auto RD_B = [&](int regionByte) {
#pragma unroll
    for (int ni = 0; ni < 2; ++ni) {
      b[ni][0] = *(const short8*)(ldsb + regionByte + boff0 + ni * 2048 + sl0);
      b[ni][1] = *(const short8*)(ldsb + regionByte + boff0 + ni * 2048 + sl1);
    }
  };
  auto MM = [&](int mb) {
    __builtin_amdgcn_s_setprio(1);
#pragma unroll
    for (int ks = 0; ks < 2; ++ks)
#pragma unroll
      for (int mi = 0; mi < 4; ++mi)
#pragma unroll
        for (int ni = 0; ni < 2; ++ni)
          acc[mb + mi][ni] = __builtin_amdgcn_mfma_f32_16x16x32_bf16(
              a[mi][ks], b[ni][ks], acc[mb + mi][ni], 0, 0, 0);
    __builtin_amdgcn_s_setprio(0);
  };

  // prologue: tile0 -> d0, tile1 -> odd[0]; wait tile0 (6 of 12 loads)
  STG_B(0, 32768); STG_A(0, 0, 0); STG_A(0, 1, 0);
  STG_A(1, 0, 49152); STG_A(1, 1, 49152); STG_B(1, 114688);
  VMW(6); BAR();

  auto ITER = [&](int j, int pr, bool last) {
    const int e2 = 2 * j + 2, o2 = 2 * j + 3;
    const int OA = 49152 + pr * 32768, OAs = 49152 + (1 - pr) * 32768;
    const int OB = 114688 + pr * 16384, OBs = 114688 + (1 - pr) * 16384;
    // ph0: tile e (d0), LO
    RD_A(0, 0); RD_B(32768); STG_A(o2, 0, OAs);
    BAR(); LGKM0(); MM(0); BAR();
    // ph1: tile e, HI
    RD_A(0, 4); STG_A(o2, 1, OAs); STG_B(e2, 32768);
    BAR(); LGKM0(); MM(4);
    if (last) { VMW(0); } else { VMW(6); }
    BAR();
    // ph2: tile o (odd[pr]), LO
    RD_A(OA, 0); RD_B(OB); STG_A(e2, 0, 0); STG_A(e2, 1, 0); STG_B(o2, OBs);
    BAR(); LGKM0(); MM(0); BAR();
    // ph3: tile o, HI
    RD_A(OA, 4);
    BAR(); LGKM0(); MM(4);
    if (last) { VMW(0); } else { VMW(2); }
    BAR();
  };

#pragma unroll 1
  for (int jj = 0; jj < 4; ++jj) {
    ITER(2 * jj, 0, false);
    ITER(2 * jj + 1, 1, jj == 3);
  }

  // epilogue: out = z*h + (1-z)*tanh(s)
  const int row0 = bm * 256 + wm * 128 + kg * 4;
  const int col0 = bn * 128 + wn * 32 + rsel;
#pragma unroll
  for (int mf = 0; mf < 8; ++mf)
#pragma unroll
    for (int nf = 0; nf < 2; ++nf)
#pragma unroll
      for (int q = 0; q < 4; ++q) {
        const int row = row0 + mf * 16 + q;
        const int col = col0 + nf * 16;
        const size_t idx = (size_t)row * 512 + col;
        const float s = acc[mf][nf][q];
        const float hh = 2.f / (1.f + __expf(-2.f * s)) - 1.f;  // tanh
        const float z = b2f(zb_in[idx]);
        o_f[idx] = z * b2f(hb[idx]) + (1.f - z) * hh;
      }
}

// ---------------- launch ----------------
extern "C" void kernel_launch(void* const* d_in, const int* in_sizes, int n_in,
                              void* d_out, int out_size, void* d_ws, size_t ws_size,
                              hipStream_t stream) {
  const float* inputs = (const float*)d_in[0];
  const float* h_prev = (const float*)d_in[1];
  const float* Wz = (const float*)d_in[2];
  const float* Wr = (const float*)d_in[3];
  const float* Wh = (const float*)d_in[4];
  float* out = (float*)d_out;

  const int B = 16384, D = 512, U = 512, K = 1024;

  u16* xb = (u16*)d_ws;                 // [B,D] bf16
  u16* hb = xb + (size_t)B * D;         // [B,U] bf16
  u16* wzt = hb + (size_t)B * U;        // [1024,1024]: rows 0-511 Wz^T, 512-1023 Wr^T
  u16* wrt = wzt + (size_t)K * U;
  u16* wht = wrt + (size_t)K * U;       // [512,1024] Wh^T
  u16* zb = wht + (size_t)K * U;        // [B,U] bf16
  u16* rhb = zb + (size_t)B * U;        // [B,U] bf16

  const int n4 = (B * D) / 4;
  cvt_bf16_kernel<<<(n4 + 255) / 256, 256, 0, stream>>>(inputs, xb, n4);
  cvt_bf16_kernel<<<(n4 + 255) / 256, 256, 0, stream>>>(h_prev, hb, n4);
  dim3 tg((K * U + 255) / 256, 3);
  cvt_transpose_kernel<<<tg, 256, 0, stream>>>(Wz, Wr, Wh, wzt, wrt, wht, K, U);

  gemm_gates_kernel<<<dim3(256), 512, 0, stream>>>(xb, hb, wzt, zb, rhb);
  gemm_cand_kernel<<<dim3(256), 512, 0, stream>>>(xb, rhb, wht, hb, zb, out);
}

// Round 8
// 101.699 us; speedup vs baseline: 1.1784x; 1.0019x over previous
//
#include <hip/hip_runtime.h>
#include <hip/hip_bf16.h>
#include <stdint.h>

typedef __attribute__((ext_vector_type(8))) short short8;
typedef __attribute__((ext_vector_type(4))) float f32x4;
typedef unsigned short u16;

#define AS1 __attribute__((address_space(1)))
#define AS3 __attribute__((address_space(3)))

__device__ __forceinline__ u16 f2b(float f) {
  union { float f; uint32_t u; } c; c.f = f;
  uint32_t u = c.u;
  return (u16)((u + 0x7fffu + ((u >> 16) & 1u)) >> 16);  // RNE
}
__device__ __forceinline__ float b2f(u16 b) {
  union { uint32_t u; float f; } c; c.u = ((uint32_t)b) << 16;
  return c.f;
}

// ---------------- conversion kernels (verified round 1) ----------------
__global__ void cvt_bf16_kernel(const float* __restrict__ src,
                                u16* __restrict__ dst, int n4) {
  int i = blockIdx.x * blockDim.x + threadIdx.x;
  if (i >= n4) return;
  const float4 v = reinterpret_cast<const float4*>(src)[i];
  ushort4 o;
  o.x = f2b(v.x); o.y = f2b(v.y); o.z = f2b(v.z); o.w = f2b(v.w);
  reinterpret_cast<ushort4*>(dst)[i] = o;
}

__global__ void cvt_transpose_kernel(const float* __restrict__ w0,
                                     const float* __restrict__ w1,
                                     const float* __restrict__ w2,
                                     u16* __restrict__ d0,
                                     u16* __restrict__ d1,
                                     u16* __restrict__ d2,
                                     int K, int N) {
  const float* src = (blockIdx.y == 0) ? w0 : (blockIdx.y == 1 ? w1 : w2);
  u16* dst = (blockIdx.y == 0) ? d0 : (blockIdx.y == 1 ? d1 : d2);
  int idx = blockIdx.x * blockDim.x + threadIdx.x;
  if (idx >= K * N) return;
  int k = idx / N, n = idx - k * N;
  dst[(size_t)n * K + k] = f2b(src[idx]);
}

// De-pinned sync primitives (round 8): compiler schedules ds_read waits
// itself (fine-grained lgkmcnt per-MFMA, m97-style).  We fence only what
// the compiler cannot know: global_load_lds completion (counted vmcnt,
// "memory" clobber blocks memory ops from crossing) and workgroup barriers.
#define BAR() __builtin_amdgcn_s_barrier()
#define VMW(n) asm volatile("s_waitcnt vmcnt(" #n ")" ::: "memory")

// ---------------- GATES: 8-phase structure (r5 schedule, de-pinned) -------
// C[16384,1024] = [x|h] @ [Wz^T;Wr^T]^T.  BM=256, BN=256, BK=64, NT=16,
// 8 iters x 2 tiles.  512 thr = 8 waves 2Mx4N (wave 128x64, MQ=4).
// Stage stream/iter: ph0:A0(t1) ph1:A1(t1) ph2:B0(t2) ph3:B1(t2)
//   ph4:A0(t2) ph5:A1(t2) ph6:B0(t3) ph7:B1(t3)   (2 loads each).
// VMW(4)@ph3-end: drains everything except ph2+ph3's 4 -> tile t1 landed.
// VMW(4)@ph7-end: leaves ph6+ph7's 4 -> tile t2 landed.  Last iter: 0.
// WAR: each region staged >=1 barrier after its last read (A read ph0/ph2,
// staged ph4/ph5; B read ph0/ph1, staged ph2/ph3 NEXT dbuf; mirrored +4).
__global__ __launch_bounds__(512, 1) void gemm_gates_kernel(
    const u16* __restrict__ xb, const u16* __restrict__ hb,
    const u16* __restrict__ wt,
    u16* __restrict__ o_z, u16* __restrict__ o_rh) {
  constexpr int NT = 16, NITER = 8;
  __shared__ u16 lds[65536];          // 2 dbuf x 32768 e (A 32KB + B 32KB)
  const char* ldsb = (const char*)lds;

  const int tid = threadIdx.x;
  const int lane = tid & 63;
  const int wid = tid >> 6;
  const int wm = wid >> 2, wn = wid & 3;
  const int wg = ((int)blockIdx.x & 7) * 32 + ((int)blockIdx.x >> 3);
  const int bn = wg & 3, bm = wg >> 2;

  const int srow8 = tid >> 3;
  const int swzb = ((tid & 7) ^ (srow8 & 7)) << 4;
  auto STAGE = [&](int t, int kind) {
    if (t >= NT) return;
    u16* dst = lds + (t & 1) * 32768 + kind * 8192 + wid * 512;
    if (kind < 2) {  // A half (128 rows)
      const char* src = ((t < 8) ? ((const char*)xb + (size_t)t * 128)
                                 : ((const char*)hb + (size_t)(t - 8) * 128)) +
                        (size_t)(bm * 256 + kind * 128 + srow8) * 1024 + swzb;
      __builtin_amdgcn_global_load_lds((const AS1 void*)src, (AS3 void*)dst, 16, 0, 0);
      __builtin_amdgcn_global_load_lds((const AS1 void*)(src + 65536), (AS3 void*)(dst + 4096), 16, 0, 0);
    } else {         // B half (128 rows of the 256-row Wt tile)
      const char* src = (const char*)wt +
                        (size_t)(bn * 256 + (kind - 2) * 128 + srow8) * 2048 +
                        (size_t)t * 128 + swzb;
      __builtin_amdgcn_global_load_lds((const AS1 void*)src, (AS3 void*)dst, 16, 0, 0);
      __builtin_amdgcn_global_load_lds((const AS1 void*)(src + 131072), (AS3 void*)(dst + 4096), 16, 0, 0);
    }
  };

  const int rsel = lane & 15;
  const int kg = lane >> 4;
  const int sl0 = (kg ^ (rsel & 7)) << 4;
  const int sl1 = ((4 + kg) ^ (rsel & 7)) << 4;
  const int aoff0 = wm * 16384 + rsel * 128;
  const int boff0 = 32768 + wn * 8192 + rsel * 128;

  f32x4 acc[8][4] = {};
  short8 a[4][2], b[4][2];

  auto ldA = [&](int DB, int mfb) {
#pragma unroll
    for (int mi = 0; mi < 4; ++mi) {
      a[mi][0] = *(const short8*)(ldsb + DB + aoff0 + (mfb + mi) * 2048 + sl0);
      a[mi][1] = *(const short8*)(ldsb + DB + aoff0 + (mfb + mi) * 2048 + sl1);
    }
  };
  auto ldB = [&](int DB, int nfb) {
#pragma unroll
    for (int ni = 0; ni < 2; ++ni) {
      b[nfb + ni][0] = *(const short8*)(ldsb + DB + boff0 + (nfb + ni) * 2048 + sl0);
      b[nfb + ni][1] = *(const short8*)(ldsb + DB + boff0 + (nfb + ni) * 2048 + sl1);
    }
  };
  auto MM = [&](int mb, int nb) {
    __builtin_amdgcn_s_setprio(1);
#pragma unroll
    for (int ks = 0; ks < 2; ++ks)
#pragma unroll
      for (int mi = 0; mi < 4; ++mi)
#pragma unroll
        for (int ni = 0; ni < 2; ++ni)
          acc[mb + mi][nb + ni] = __builtin_amdgcn_mfma_f32_16x16x32_bf16(
              a[mi][ks], b[nb + ni][ks], acc[mb + mi][nb + ni], 0, 0, 0);
    __builtin_amdgcn_s_setprio(0);
  };

  STAGE(0, 2); STAGE(0, 3); STAGE(0, 0); STAGE(0, 1); STAGE(1, 2); STAGE(1, 3);
  VMW(4); BAR();

#pragma unroll 1
  for (int j = 0; j < NITER; ++j) {
    const int t1 = 2 * j + 1, t2 = 2 * j + 2, t3 = 2 * j + 3;
    // ph0
    ldA(0, 0); ldB(0, 0); STAGE(t1, 0);
    BAR(); MM(0, 0); BAR();
    // ph1
    ldB(0, 2); STAGE(t1, 1);
    BAR(); MM(0, 2); BAR();
    // ph2
    ldA(0, 4); STAGE(t2, 2);
    BAR(); MM(4, 2); BAR();
    // ph3
    STAGE(t2, 3);
    BAR(); MM(4, 0);
    if (j == NITER - 1) { VMW(0); } else { VMW(4); }
    BAR();
    // ph4
    ldA(65536, 0); ldB(65536, 0); STAGE(t2, 0);
    BAR(); MM(0, 0); BAR();
    // ph5
    ldB(65536, 2); STAGE(t2, 1);
    BAR(); MM(0, 2); BAR();
    // ph6
    ldA(65536, 4); STAGE(t3, 2);
    BAR(); MM(4, 2); BAR();
    // ph7
    STAGE(t3, 3);
    BAR(); MM(4, 0);
    if (j == NITER - 1) { VMW(0); } else { VMW(4); }
    BAR();
  }

  const int row0 = bm * 256 + wm * 128 + kg * 4;
  const int col0 = bn * 256 + wn * 64 + rsel;
  if (bn < 2) {  // z half (global cols 0..511), block-uniform
#pragma unroll
    for (int mf = 0; mf < 8; ++mf)
#pragma unroll
      for (int nf = 0; nf < 4; ++nf)
#pragma unroll
        for (int q = 0; q < 4; ++q) {
          const int row = row0 + mf * 16 + q;
          const int col = col0 + nf * 16;
          const float zf = 1.f / (1.f + __expf(-acc[mf][nf][q]));
          o_z[(size_t)row * 512 + col] = f2b(zf);
        }
  } else {       // r half (global cols 512..1023)
#pragma unroll
    for (int mf = 0; mf < 8; ++mf)
#pragma unroll
      for (int nf = 0; nf < 4; ++nf)
#pragma unroll
        for (int q = 0; q < 4; ++q) {
          const int row = row0 + mf * 16 + q;
          const int col = col0 + nf * 16 - 512;
          const size_t idx = (size_t)row * 512 + col;
          const float rf = 1.f / (1.f + __expf(-acc[mf][nf][q]));
          o_rh[idx] = f2b(rf * b2f(hb[idx]));
        }
  }
}

// ---------------- CAND: 4-phase/tile-pair (r7 schedule, de-pinned) --------
// C[16384,512] = [x|rh] @ Wh^T.  BM=256, BN=128, BK=64, NT=16, 8 iters x
// 2 tiles in 4 phases.  Waves 2Mx4N (wave 128x32, MQ=4, 2 B-frags).
// LDS 144KB: d0A[32K]@0, d0B[16K]@32768, oddA[2]x32K@49152,
// oddB[2]x16K@114688.  Stage/WAR/deadline derivation: see r7 (verified):
// VMW(6)@ph1-end (tile-odd landed), VMW(2)@ph3-end (tile e' A + d0B landed).
__global__ __launch_bounds__(512, 1) void gemm_cand_kernel(
    const u16* __restrict__ xb, const u16* __restrict__ rhb,
    const u16* __restrict__ wt, const u16* __restrict__ hb,
    const u16* __restrict__ zb_in, float* __restrict__ o_f) {
  constexpr int NT = 16;
  __shared__ u16 lds[73728];          // 147456 B
  const char* ldsb = (const char*)lds;

  const int tid = threadIdx.x;
  const int lane = tid & 63;
  const int wid = tid >> 6;
  const int wm = wid >> 2, wn = wid & 3;
  const int wg = ((int)blockIdx.x & 7) * 32 + ((int)blockIdx.x >> 3);
  const int bn = wg & 3, bm = wg >> 2;

  const int srow8 = tid >> 3;
  const int swzb = ((tid & 7) ^ (srow8 & 7)) << 4;
  auto STG_A = [&](int t, int half, int regionByte) {
    if (t >= NT) return;
    u16* dst = lds + regionByte / 2 + half * 8192 + wid * 512;
    const char* src = ((t < 8) ? ((const char*)xb + (size_t)t * 128)
                               : ((const char*)rhb + (size_t)(t - 8) * 128)) +
                      (size_t)(bm * 256 + half * 128 + srow8) * 1024 + swzb;
    __builtin_amdgcn_global_load_lds((const AS1 void*)src, (AS3 void*)dst, 16, 0, 0);
    __builtin_amdgcn_global_load_lds((const AS1 void*)(src + 65536), (AS3 void*)(dst + 4096), 16, 0, 0);
  };
  auto STG_B = [&](int t, int regionByte) {
    if (t >= NT) return;
    u16* dst = lds + regionByte / 2 + wid * 512;
    const char* src = (const char*)wt + (size_t)(bn * 128 + srow8) * 2048 +
                      (size_t)t * 128 + swzb;
    __builtin_amdgcn_global_load_lds((const AS1 void*)src, (AS3 void*)dst, 16, 0, 0);
    __builtin_amdgcn_global_load_lds((const AS1 void*)(src + 131072), (AS3 void*)(dst + 4096), 16, 0, 0);
  };

  const int rsel = lane & 15;
  const int kg = lane >> 4;
  const int sl0 = (kg ^ (rsel & 7)) << 4;
  const int sl1 = ((4 + kg) ^ (rsel & 7)) << 4;
  const int aoff0 = wm * 16384 + rsel * 128;
  const int boff0 = wn * 4096 + rsel * 128;

  f32x4 acc[8][2] = {};
  short8 a[4][2], b[2][2];

  auto RD_A = [&](int regionByte, int mfb) {
#pragma unroll
    for (int mi = 0; mi < 4; ++mi) {
      a[mi][0] = *(const short8*)(ldsb + regionByte + aoff0 + (mfb + mi) * 2048 + sl0);
      a[mi][1] = *(const short8*)(ldsb + regionByte + aoff0 + (mfb + mi) * 2048 + sl1);
    }
  };
  auto RD_B = [&](int regionByte) {
#pragma unroll
    for (int ni = 0; ni < 2; ++ni) {
      b[ni][0] = *(const short8*)(ldsb + regionByte + boff0 + ni * 2048 + sl0);
      b[ni][1] = *(const short8*)(ldsb + regionByte + boff0 + ni * 2048 + sl1);
    }
  };
  auto MM = [&](int mb) {
    __builtin_amdgcn_s_setprio(1);
#pragma unroll
    for (int ks = 0; ks < 2; ++ks)
#pragma unroll
      for (int mi = 0; mi < 4; ++mi)
#pragma unroll
        for (int ni = 0; ni < 2; ++ni)
          acc[mb + mi][ni] = __builtin_amdgcn_mfma_f32_16x16x32_bf16(
              a[mi][ks], b[ni][ks], acc[mb + mi][ni], 0, 0, 0);
    __builtin_amdgcn_s_setprio(0);
  };

  // prologue: tile0 -> d0, tile1 -> odd[0]; wait tile0 (6 of 12 loads)
  STG_B(0, 32768); STG_A(0, 0, 0); STG_A(0, 1, 0);
  STG_A(1, 0, 49152); STG_A(1, 1, 49152); STG_B(1, 114688);
  VMW(6); BAR();

  auto ITER = [&](int j, int pr, bool last) {
    const int e2 = 2 * j + 2, o2 = 2 * j + 3;
    const int OA = 49152 + pr * 32768, OAs = 49152 + (1 - pr) * 32768;
    const int OB = 114688 + pr * 16384, OBs = 114688 + (1 - pr) * 16384;
    // ph0: tile e (d0), LO
    RD_A(0, 0); RD_B(32768); STG_A(o2, 0, OAs);
    BAR(); MM(0); BAR();
    // ph1: tile e, HI
    RD_A(0, 4); STG_A(o2, 1, OAs); STG_B(e2, 32768);
    BAR(); MM(4);
    if (last) { VMW(0); } else { VMW(6); }
    BAR();
    // ph2: tile o (odd[pr]), LO
    RD_A(OA, 0); RD_B(OB); STG_A(e2, 0, 0); STG_A(e2, 1, 0); STG_B(o2, OBs);
    BAR(); MM(0); BAR();
    // ph3: tile o, HI
    RD_A(OA, 4);
    BAR(); MM(4);
    if (last) { VMW(0); } else { VMW(2); }
    BAR();
  };

#pragma unroll 1
  for (int jj = 0; jj < 4; ++jj) {
    ITER(2 * jj, 0, false);
    ITER(2 * jj + 1, 1, jj == 3);
  }

  // epilogue: out = z*h + (1-z)*tanh(s)
  const int row0 = bm * 256 + wm * 128 + kg * 4;
  const int col0 = bn * 128 + wn * 32 + rsel;
#pragma unroll
  for (int mf = 0; mf < 8; ++mf)
#pragma unroll
    for (int nf = 0; nf < 2; ++nf)
#pragma unroll
      for (int q = 0; q < 4; ++q) {
        const int row = row0 + mf * 16 + q;
        const int col = col0 + nf * 16;
        const size_t idx = (size_t)row * 512 + col;
        const float s = acc[mf][nf][q];
        const float hh = 2.f / (1.f + __expf(-2.f * s)) - 1.f;  // tanh
        const float z = b2f(zb_in[idx]);
        o_f[idx] = z * b2f(hb[idx]) + (1.f - z) * hh;
      }
}

// ---------------- launch ----------------
extern "C" void kernel_launch(void* const* d_in, const int* in_sizes, int n_in,
                              void* d_out, int out_size, void* d_ws, size_t ws_size,
                              hipStream_t stream) {
  const float* inputs = (const float*)d_in[0];
  const float* h_prev = (const float*)d_in[1];
  const float* Wz = (const float*)d_in[2];
  const float* Wr = (const float*)d_in[3];
  const float* Wh = (const float*)d_in[4];
  float* out = (float*)d_out;

  const int B = 16384, D = 512, U = 512, K = 1024;

  u16* xb = (u16*)d_ws;                 // [B,D] bf16
  u16* hb = xb + (size_t)B * D;         // [B,U] bf16
  u16* wzt = hb + (size_t)B * U;        // [1024,1024]: rows 0-511 Wz^T, 512-1023 Wr^T
  u16* wrt = wzt + (size_t)K * U;
  u16* wht = wrt + (size_t)K * U;       // [512,1024] Wh^T
  u16* zb = wht + (size_t)K * U;        // [B,U] bf16
  u16* rhb = zb + (size_t)B * U;        // [B,U] bf16

  const int n4 = (B * D) / 4;
  cvt_bf16_kernel<<<(n4 + 255) / 256, 256, 0, stream>>>(inputs, xb, n4);
  cvt_bf16_kernel<<<(n4 + 255) / 256, 256, 0, stream>>>(h_prev, hb, n4);
  dim3 tg((K * U + 255) / 256, 3);
  cvt_transpose_kernel<<<tg, 256, 0, stream>>>(Wz, Wr, Wh, wzt, wrt, wht, K, U);

  gemm_gates_kernel<<<dim3(256), 512, 0, stream>>>(xb, hb, wzt, zb, rhb);
  gemm_cand_kernel<<<dim3(256), 512, 0, stream>>>(xb, rhb, wht, hb, zb, out);
}